// Round 2
// baseline (582.257 us; speedup 1.0000x reference)
//
#include <hip/hip_runtime.h>
#include <math.h>

// MFMA fragment types (gfx950, 16x16x32 f16: 8 halves A/B, 4 floats C/D)
typedef _Float16 v8h  __attribute__((ext_vector_type(8)));
typedef _Float16 h4   __attribute__((ext_vector_type(4)));
typedef float    fx4  __attribute__((ext_vector_type(4)));

#define S1_FRAGS 18   // 6 n-tiles * 3 k-steps  (DCT matrix, 96x96)
#define S2_FRAGS 36   // 12 n-tiles * 3 k-steps (W1, 192x96)
#define S3_FRAGS 36   // 6 n-tiles * 6 k-steps  (W2, 96x192)

// Pre-gather weight fragments in MFMA lane order. NOTE: A-frag and B-frag
// lane mappings coincide under m<->n swap (lane&15 selects m for A, n for B;
// lane>>4 selects the k-octet for both), so these frags serve as A-operands
// in the transposed dataflow unchanged.
__global__ void prep_frags(const float* __restrict__ W1,
                           const float* __restrict__ W2,
                           v8h* __restrict__ ws) {
    const int f    = blockIdx.x;    // 0..89
    const int lane = threadIdx.x;   // 0..63
    v8h v;
    if (f < S1_FRAGS) {
        const int t = f / 3, s = f % 3;
        const int n  = t * 16 + (lane & 15);        // DCT output index k_out
        const int k0 = s * 32 + (lane >> 4) * 8;    // input index i
#pragma unroll
        for (int j = 0; j < 8; ++j) {
            const int i = k0 + j;
            const float ang = 3.14159265358979323846f * (float)((2 * i + 1) * n) / 192.0f;
            v[j] = (_Float16)(2.0f * cosf(ang));
        }
    } else if (f < S1_FRAGS + S2_FRAGS) {
        const int g = f - S1_FRAGS;
        const int t = g / 3, s = g % 3;
        const int n  = t * 16 + (lane & 15);
        const int k0 = s * 32 + (lane >> 4) * 8;
#pragma unroll
        for (int j = 0; j < 8; ++j) v[j] = (_Float16)W1[n * 96 + k0 + j];
    } else {
        const int g = f - S1_FRAGS - S2_FRAGS;
        const int t = g / 6, s = g % 6;
        const int n  = t * 16 + (lane & 15);
        const int k0 = s * 32 + (lane >> 4) * 8;
#pragma unroll
        for (int j = 0; j < 8; ++j) v[j] = (_Float16)W2[n * 192 + k0 + j];
    }
    ws[f * 64 + lane] = v;
}

#define LDA 104          // f16 leading dim, lr overlay (96+8, rows 16B-aligned)
#define LDH 200          // f16 leading dim, h overlay (192+8, rows 16B-aligned)
#define CHUNK (16 * LDH) // 3200 f16 = 6.4 KB per wave; lr overlay aliases it.
                         // Safe: DS ops are in-order per wave and all lr reads
                         // precede h writes in program order; chunks are
                         // wave-private so no cross-wave hazard.

// Transposed dataflow: every MFMA is D = weight_frag (A) * activation (B),
// so each lane's C-registers hold 24 values of ONE data row (lane&15) at
// cols 16t + (lane>>4)*4 + r. LN reductions are 2 shfl_xor steps (lanes
// ^16, ^32); all LDS/global epilogues are 4-contiguous vector ops.
__global__ __launch_bounds__(256, 6)
void fused_dct_mlp(const float* __restrict__ x,
                   const float* __restrict__ gamma,
                   const float* __restrict__ beta,
                   const v8h* __restrict__ wf,
                   float* __restrict__ out) {
    __shared__ __align__(16) _Float16 BUF[4][CHUNK];

    const int tid  = threadIdx.x;
    const int lane = tid & 63;
    const int wave = tid >> 6;
    const int lr_  = lane & 15;         // this lane's data row (wave-local)
    const int lk   = lane >> 4;         // k-octet / col-quad selector

    _Float16* const base = &BUF[wave][0];
    const long row  = (long)blockIdx.x * 64 + wave * 16 + lr_;  // global data row
    const float* arow = x + row * 96;

    // ---------------- stage 1: dct^T = D * x^T ----------------
    // B-frag (x^T): lane holds x[row][s*32 + lk*8 + j] — issue all 6 16B
    // loads up front, then convert.
    fx4 xa[6];
#pragma unroll
    for (int s = 0; s < 3; ++s) {
        const float* ap = arow + s * 32 + lk * 8;
        xa[2 * s]     = *(const fx4*)ap;
        xa[2 * s + 1] = *(const fx4*)(ap + 4);
    }
    v8h xf[3];
#pragma unroll
    for (int s = 0; s < 3; ++s)
#pragma unroll
        for (int j = 0; j < 4; ++j) {
            xf[s][j]     = (_Float16)xa[2 * s][j];
            xf[s][4 + j] = (_Float16)xa[2 * s + 1][j];
        }

    fx4 acc1[6];
#pragma unroll
    for (int t = 0; t < 6; ++t) acc1[t] = (fx4){0.f, 0.f, 0.f, 0.f};
#pragma unroll
    for (int s = 0; s < 3; ++s)
#pragma unroll
        for (int t = 0; t < 6; ++t)
            acc1[t] = __builtin_amdgcn_mfma_f32_16x16x32_f16(
                wf[(t * 3 + s) * 64 + lane], xf[s], acc1[t], 0, 0, 0);

    // ---- LN1 from C-registers (lane owns row lr_, cols 16t+lk*4+r) ----
    {
        float sum = 0.f, sq = 0.f;
#pragma unroll
        for (int t = 0; t < 6; ++t)
#pragma unroll
            for (int r = 0; r < 4; ++r) { float v = acc1[t][r]; sum += v; sq += v * v; }
        sum += __shfl_xor(sum, 16); sq += __shfl_xor(sq, 16);
        sum += __shfl_xor(sum, 32); sq += __shfl_xor(sq, 32);
        const float mu = sum * (1.0f / 96.0f);
        const float rs = rsqrtf(sq * (1.0f / 96.0f) - mu * mu + 1e-6f);
#pragma unroll
        for (int t = 0; t < 6; ++t) {
            const int c0 = t * 16 + lk * 4;
            const fx4 g  = *(const fx4*)(gamma + c0);
            const fx4 bb = *(const fx4*)(beta + c0);
            h4 p;
#pragma unroll
            for (int r = 0; r < 4; ++r)
                p[r] = (_Float16)((acc1[t][r] - mu) * rs * g[r] + bb[r]);
            *(h4*)(base + lr_ * LDA + c0) = p;   // ds_write_b64
        }
    }

    // ---------------- stage 2: h^T = W1 * lr^T ----------------
    fx4 acc2[12];
#pragma unroll
    for (int t = 0; t < 12; ++t) acc2[t] = (fx4){0.f, 0.f, 0.f, 0.f};
#pragma unroll
    for (int s = 0; s < 3; ++s) {
        const v8h af = *(const v8h*)(base + lr_ * LDA + s * 32 + lk * 8);  // ds_read_b128
        const v8h* bp = wf + S1_FRAGS * 64;
#pragma unroll
        for (int t = 0; t < 12; ++t)
            acc2[t] = __builtin_amdgcn_mfma_f32_16x16x32_f16(
                bp[(t * 3 + s) * 64 + lane], af, acc2[t], 0, 0, 0);
    }
    // relu -> h overlay (aliases lr overlay; all lr reads already issued)
#pragma unroll
    for (int t = 0; t < 12; ++t) {
        h4 p;
#pragma unroll
        for (int r = 0; r < 4; ++r) p[r] = (_Float16)fmaxf(acc2[t][r], 0.0f);
        *(h4*)(base + lr_ * LDH + t * 16 + lk * 4) = p;   // ds_write_b64
    }

    // ---------------- stage 3: s^T = W2 * h^T ----------------
    fx4 acc3[6];
#pragma unroll
    for (int t = 0; t < 6; ++t) acc3[t] = (fx4){0.f, 0.f, 0.f, 0.f};
#pragma unroll
    for (int s = 0; s < 6; ++s) {
        const v8h hf = *(const v8h*)(base + lr_ * LDH + s * 32 + lk * 8);  // ds_read_b128
        const v8h* bp = wf + (S1_FRAGS + S2_FRAGS) * 64;
#pragma unroll
        for (int t = 0; t < 6; ++t)
            acc3[t] = __builtin_amdgcn_mfma_f32_16x16x32_f16(
                bp[(t * 6 + s) * 64 + lane], hf, acc3[t], 0, 0, 0);
    }
#pragma unroll
    for (int t = 0; t < 6; ++t)
#pragma unroll
        for (int r = 0; r < 4; ++r)
            acc3[t][r] = 1.0f / (1.0f + __expf(-acc3[t][r]));

    // ---- LN2 from C-registers + out = x * w, float4 I/O ----
    {
        float sum = 0.f, sq = 0.f;
#pragma unroll
        for (int t = 0; t < 6; ++t)
#pragma unroll
            for (int r = 0; r < 4; ++r) { float v = acc3[t][r]; sum += v; sq += v * v; }
        sum += __shfl_xor(sum, 16); sq += __shfl_xor(sq, 16);
        sum += __shfl_xor(sum, 32); sq += __shfl_xor(sq, 32);
        const float mu = sum * (1.0f / 96.0f);
        const float rs = rsqrtf(sq * (1.0f / 96.0f) - mu * mu + 1e-6f);
#pragma unroll
        for (int t = 0; t < 6; ++t) {
            const int c0 = t * 16 + lk * 4;
            const fx4 g  = *(const fx4*)(gamma + c0);
            const fx4 bb = *(const fx4*)(beta + c0);
            const fx4 xv = *(const fx4*)(arow + c0);   // L2-hot re-read
            fx4 o;
#pragma unroll
            for (int r = 0; r < 4; ++r)
                o[r] = xv[r] * ((acc3[t][r] - mu) * rs * g[r] + bb[r]);
            *(fx4*)(out + row * 96 + c0) = o;          // global_store_dwordx4
        }
    }
}

extern "C" void kernel_launch(void* const* d_in, const int* in_sizes, int n_in,
                              void* d_out, int out_size, void* d_ws, size_t ws_size,
                              hipStream_t stream) {
    const float* x     = (const float*)d_in[0];
    const float* W1    = (const float*)d_in[1];
    const float* W2    = (const float*)d_in[2];
    const float* gamma = (const float*)d_in[3];
    const float* beta  = (const float*)d_in[4];
    float* out = (float*)d_out;
    v8h* ws = (v8h*)d_ws;   // 90 KB of pre-gathered weight fragments

    prep_frags<<<S1_FRAGS + S2_FRAGS + S3_FRAGS, 64, 0, stream>>>(W1, W2, ws);

    const long rows = (long)in_sizes[0] / 96;   // 524288
    fused_dct_mlp<<<(int)(rows / 64), 256, 0, stream>>>(x, gamma, beta, ws, out);
}